// Round 5
// baseline (276.972 us; speedup 1.0000x reference)
//
#include <hip/hip_runtime.h>
#include <math.h>

#define N_NODES 50000
#define N_EDGES 800000
#define HIDDEN  64
#define NPART   500                   // partition blocks
#define PCHUNK  1600                  // edges per partition block
#define NBUCK   32
#define SLICE   1568                  // 32*1568 = 50176 >= 50000
#define CAPB    128                   // per-(block,bucket) stage cap
#define BCAP    26000                 // dense bucket capacity
#define NSUB    16                    // agg sub-blocks per bucket -> 512 agg blocks (2/CU)

// R3 post-mortem: agg-interior changes (NSUB 8->16, uint4 gathers) were a null result ->
// our ~30us budget is dispatch-count-dominated (~1.5-2us fixed cost x 8 dispatches).
// R4: fold k_g/k_mlp/k_final into the preceding agg kernel as last-block-per-bucket tails
// (atomic counter + threadfence handshake, no spinning -> dispatch-order-safe). 8 -> 5 dispatches.

// ---- K1: write-combined radix partition, DENSE flush via bucket-tail reservation ----
__global__ __launch_bounds__(256)
void k_part(const int* __restrict__ row, const int* __restrict__ col,
            unsigned* __restrict__ tails, unsigned* __restrict__ bks) {
    __shared__ unsigned stage[NBUCK * CAPB];        // 16 KB
    __shared__ unsigned cnt2[NBUCK], gpos[NBUCK];
    const int t   = threadIdx.x;
    const int blk = blockIdx.x;
    const int e0  = blk * PCHUNK;
    if (t < NBUCK) cnt2[t] = 0u;
    __syncthreads();
    const int4* c4 = (const int4*)(col + e0);
    const int4* r4 = (const int4*)(row + e0);
    for (int i = t; i < PCHUNK / 4; i += 256) {     // 400 int4s
        int4 cv = c4[i];
        int4 rv = r4[i];
#pragma unroll
        for (int k = 0; k < 4; ++k) {
            int c = (&cv.x)[k], r = (&rv.x)[k];
            int b = c / SLICE;                      // magic-mul div
            unsigned off = atomicAdd(&cnt2[b], 1u);
            if (off < CAPB)
                stage[(b << 7) + off] = ((unsigned)(c - b * SLICE) << 16) | (unsigned)r;
        }
    }
    __syncthreads();
    if (t < NBUCK) {
        unsigned cc = min(cnt2[t], (unsigned)CAPB);
        cnt2[t] = cc;
        gpos[t] = atomicAdd(&tails[t], cc);
    }
    __syncthreads();
    for (int i = t; i < NBUCK * CAPB; i += 256) {
        int b = i >> 7; unsigned o = (unsigned)(i & 127);
        if (o < cnt2[b]) {
            unsigned dst = gpos[b] + o;
            if (dst < BCAP) bks[(size_t)b * BCAP + dst] = stage[i];
        }
    }
}

// chunk bounds for a sub-block, 4-aligned so uint4 loads stay aligned
__device__ __forceinline__ void sub_range(unsigned tail, int s, unsigned& lo, unsigned& hi) {
    unsigned chunk = ((tail + NSUB - 1) / NSUB + 3u) & ~3u;
    lo = s * chunk;
    hi = min(lo + chunk, tail);
    if (lo > tail) lo = tail;
}

// producer->last-block handshake. Returns true on the last block of the bucket.
// Producers fence once and exit (no spin -> no deadlock, no dispatch-order assumption).
__device__ __forceinline__ bool last_block(unsigned* cnt, int b, unsigned* lastflag) {
    __threadfence();                    // make this thread's partial stores device-visible
    __syncthreads();                    // all threads fenced
    if (threadIdx.x == 0)
        *lastflag = (atomicAdd(&cnt[b], 1u) == NSUB - 1u) ? 1u : 0u;
    __syncthreads();
    if (*lastflag == 0u) return false;
    __threadfence();                    // acquire: invalidate stale cached lines
    return true;
}

// ---- K2: per-slice degree partials + last-block reduce -> dinv, g ----
__global__ __launch_bounds__(256)
void k_degg(const unsigned* __restrict__ tails, const unsigned* __restrict__ bks,
            unsigned* __restrict__ part_deg, unsigned* __restrict__ cnt,
            const float* __restrict__ x, float* __restrict__ dinv, float* __restrict__ g) {
    __shared__ unsigned acc[SLICE];                 // 6.3 KB
    __shared__ unsigned lastflag;
    const int t = threadIdx.x;
    const int b = blockIdx.x >> 4;
    const int s = blockIdx.x & (NSUB - 1);
    for (int i = t; i < SLICE; i += 256) acc[i] = 0u;
    __syncthreads();
    unsigned tail = min(tails[b], (unsigned)BCAP);
    unsigned lo, hi; sub_range(tail, s, lo, hi);
    const unsigned* bk = bks + (size_t)b * BCAP;
    const uint4* bk4 = (const uint4*)bk;
    unsigned hiv = hi & ~3u;
    for (unsigned i = (lo >> 2) + t; (i << 2) < hiv; i += 256) {
        uint4 v4 = bk4[i];
#pragma unroll
        for (int k = 0; k < 4; ++k) atomicAdd(&acc[(&v4.x)[k] >> 16], 1u);
    }
    for (unsigned i = hiv + t; i < hi; i += 256)
        atomicAdd(&acc[bk[i] >> 16], 1u);
    __syncthreads();
    unsigned* dst = part_deg + (size_t)blockIdx.x * SLICE;
    for (int i = t; i < SLICE; i += 256) dst[i] = acc[i];

    if (!last_block(cnt, b, &lastflag)) return;
    // reduce tail: this bucket's 1568 nodes
    const unsigned* pd = part_deg + (size_t)b * NSUB * SLICE;
    for (int i = t; i < SLICE; i += 256) {
        int n = b * SLICE + i;
        if (n >= N_NODES) continue;
        unsigned d = 0;
#pragma unroll
        for (int s2 = 0; s2 < NSUB; ++s2) d += pd[(size_t)s2 * SLICE + i];
        float di = rsqrtf((float)(d + 1u));         // +1 self-loop
        dinv[n] = di;
        g[n] = di * x[n];
    }
}

// ---- K3: layer-1 aggregation + last-block {reduce + fused MLP} -> z ----
__global__ __launch_bounds__(256)
void k_agg1mlp(const unsigned* __restrict__ tails, const unsigned* __restrict__ bks,
               const float* __restrict__ g, const float* __restrict__ dinv,
               const float* __restrict__ W1, const float* __restrict__ b1,
               const float* __restrict__ W2,
               float* __restrict__ part1, unsigned* __restrict__ cnt,
               float2* __restrict__ z) {
    __shared__ float acc[SLICE];
    __shared__ unsigned lastflag;
    const int t = threadIdx.x;
    const int b = blockIdx.x >> 4;
    const int s = blockIdx.x & (NSUB - 1);
    for (int i = t; i < SLICE; i += 256) acc[i] = 0.0f;
    __syncthreads();
    unsigned tail = min(tails[b], (unsigned)BCAP);
    unsigned lo, hi; sub_range(tail, s, lo, hi);
    const unsigned* bk = bks + (size_t)b * BCAP;
    const uint4* bk4 = (const uint4*)bk;
    unsigned hiv = hi & ~3u;
    for (unsigned i = (lo >> 2) + t; (i << 2) < hiv; i += 256) {
        uint4 v4 = bk4[i];
        float g0 = g[v4.x & 0xFFFFu];
        float g1 = g[v4.y & 0xFFFFu];
        float g2 = g[v4.z & 0xFFFFu];
        float g3 = g[v4.w & 0xFFFFu];
        atomicAdd(&acc[v4.x >> 16], g0);
        atomicAdd(&acc[v4.y >> 16], g1);
        atomicAdd(&acc[v4.z >> 16], g2);
        atomicAdd(&acc[v4.w >> 16], g3);
    }
    for (unsigned i = hiv + t; i < hi; i += 256) {
        unsigned v = bk[i];
        atomicAdd(&acc[v >> 16], g[v & 0xFFFFu]);
    }
    __syncthreads();
    float* dst = part1 + (size_t)blockIdx.x * SLICE;
    for (int i = t; i < SLICE; i += 256) dst[i] = acc[i];

    if (!last_block(cnt, b, &lastflag)) return;
    // reduce + MLP for this bucket's nodes
    const float* p1 = part1 + (size_t)b * NSUB * SLICE;
    for (int i = t; i < SLICE; i += 256) {
        int n = b * SLICE + i;
        if (n >= N_NODES) continue;
        float tt = 0.0f;
#pragma unroll
        for (int s2 = 0; s2 < NSUB; ++s2) tt += p1[(size_t)s2 * SLICE + i];
        float di = dinv[n];
        float sv = di * (tt + g[n]);
        float y0 = 0.0f, y1 = 0.0f;
#pragma unroll
        for (int k = 0; k < HIDDEN; ++k) {          // wave-uniform -> s_load
            float h = fmaxf(sv * W1[k] + b1[k], 0.0f);
            y0 += h * W2[2 * k];
            y1 += h * W2[2 * k + 1];
        }
        z[n] = make_float2(di * y0, di * y1);
    }
}

// ---- K4: layer-2 aggregation (float2) + last-block {reduce + epilogue} -> out ----
__global__ __launch_bounds__(256)
void k_agg2fin(const unsigned* __restrict__ tails, const unsigned* __restrict__ bks,
               const float2* __restrict__ z, const float* __restrict__ dinv,
               const float* __restrict__ b2,
               float2* __restrict__ part2, unsigned* __restrict__ cnt,
               float2* __restrict__ out) {
    __shared__ float ax[SLICE];
    __shared__ float ay[SLICE];
    __shared__ unsigned lastflag;
    const int t = threadIdx.x;
    const int b = blockIdx.x >> 4;
    const int s = blockIdx.x & (NSUB - 1);
    for (int i = t; i < SLICE; i += 256) { ax[i] = 0.0f; ay[i] = 0.0f; }
    __syncthreads();
    unsigned tail = min(tails[b], (unsigned)BCAP);
    unsigned lo, hi; sub_range(tail, s, lo, hi);
    const unsigned* bk = bks + (size_t)b * BCAP;
    const uint4* bk4 = (const uint4*)bk;
    unsigned hiv = hi & ~3u;
    for (unsigned i = (lo >> 2) + t; (i << 2) < hiv; i += 256) {
        uint4 v4 = bk4[i];
        float2 z0 = z[v4.x & 0xFFFFu];
        float2 z1 = z[v4.y & 0xFFFFu];
        float2 z2 = z[v4.z & 0xFFFFu];
        float2 z3 = z[v4.w & 0xFFFFu];
        atomicAdd(&ax[v4.x >> 16], z0.x); atomicAdd(&ay[v4.x >> 16], z0.y);
        atomicAdd(&ax[v4.y >> 16], z1.x); atomicAdd(&ay[v4.y >> 16], z1.y);
        atomicAdd(&ax[v4.z >> 16], z2.x); atomicAdd(&ay[v4.z >> 16], z2.y);
        atomicAdd(&ax[v4.w >> 16], z3.x); atomicAdd(&ay[v4.w >> 16], z3.y);
    }
    for (unsigned i = hiv + t; i < hi; i += 256) {
        unsigned v = bk[i];
        float2 zz = z[v & 0xFFFFu];
        atomicAdd(&ax[v >> 16], zz.x);
        atomicAdd(&ay[v >> 16], zz.y);
    }
    __syncthreads();
    float2* dst = part2 + (size_t)blockIdx.x * SLICE;
    for (int i = t; i < SLICE; i += 256) dst[i] = make_float2(ax[i], ay[i]);

    if (!last_block(cnt, b, &lastflag)) return;
    // reduce + epilogue for this bucket's nodes
    const float2* p2 = part2 + (size_t)b * NSUB * SLICE;
    for (int i = t; i < SLICE; i += 256) {
        int n = b * SLICE + i;
        if (n >= N_NODES) continue;
        float Tx = 0.0f, Ty = 0.0f;
#pragma unroll
        for (int s2 = 0; s2 < NSUB; ++s2) {
            float2 v = p2[(size_t)s2 * SLICE + i];
            Tx += v.x; Ty += v.y;
        }
        float di = dinv[n];
        float2 zn = z[n];
        out[n] = make_float2(di * (Tx + zn.x) + b2[0], di * (Ty + zn.y) + b2[1]);
    }
}

// ================= launch =================

extern "C" void kernel_launch(void* const* d_in, const int* in_sizes, int n_in,
                              void* d_out, int out_size, void* d_ws, size_t ws_size,
                              hipStream_t stream) {
    const float* x  = (const float*)d_in[0];
    const int*   ei = (const int*)d_in[1];
    const float* W1 = (const float*)d_in[2];
    const float* b1 = (const float*)d_in[3];
    const float* W2 = (const float*)d_in[4];
    const float* b2 = (const float*)d_in[5];

    const int* row = ei;
    const int* col = ei + N_EDGES;

    char* p = (char*)d_ws;
    unsigned* tails    = (unsigned*)p;  p += 128;   // 32 u32
    unsigned* c_deg    = (unsigned*)p;  p += 128;   // 32 u32 handshake counters
    unsigned* c_a1     = (unsigned*)p;  p += 128;
    unsigned* c_a2     = (unsigned*)p;  p += 128;
    unsigned* bks      = (unsigned*)p;  p += (size_t)NBUCK * BCAP * 4;             // 3.3 MB
    unsigned* part_deg = (unsigned*)p;  p += (size_t)NBUCK * NSUB * SLICE * 4;     // 3.2 MB
    float*    part1    = (float*)p;     p += (size_t)NBUCK * NSUB * SLICE * 4;     // 3.2 MB
    float2*   part2    = (float2*)p;    p += (size_t)NBUCK * NSUB * SLICE * 8;     // 6.4 MB
    float*    dinv     = (float*)p;     p += 200064;
    float*    g        = (float*)p;     p += 200064;
    float2*   z        = (float2*)p;

    const int gA = NBUCK * NSUB;            // 512 agg blocks (2 per CU)

    hipMemsetAsync(tails, 0, 512, stream);  // tails + 3 handshake counter arrays
    k_part   <<<NPART, 256, 0, stream>>>(row, col, tails, bks);
    k_degg   <<<gA,    256, 0, stream>>>(tails, bks, part_deg, c_deg, x, dinv, g);
    k_agg1mlp<<<gA,    256, 0, stream>>>(tails, bks, g, dinv, W1, b1, W2, part1, c_a1, z);
    k_agg2fin<<<gA,    256, 0, stream>>>(tails, bks, z, dinv, b2, part2, c_a2, (float2*)d_out);
}

// Round 6
// 108.172 us; speedup vs baseline: 2.5605x; 2.5605x over previous
//
#include <hip/hip_runtime.h>
#include <math.h>

#define N_NODES 50000
#define N_EDGES 800000
#define HIDDEN  64
#define NPART   500                   // partition blocks
#define PCHUNK  1600                  // edges per partition block (500*1600 = 800000)
#define NB      256                   // buckets == one block per bucket in agg kernels
#define SL      196                   // nodes per bucket; 256*196 = 50176 >= 50000
#define CAPB    32                    // per-(block,bucket) stage cap: mean 6.25, P(>=33)~4e-14
#define BCAP    3600                  // per-bucket capacity: mean 3125 + 8.5 sigma

// R5 post-mortem: __threadfence-based cross-block handshakes cost ~80us/kernel on MI355X
// (device-scope fence = per-XCD L2 writeback; 512 WGs each issuing one). NEVER handshake.
// R6 structure: 256 buckets x 1 block -> each agg block owns its bucket end-to-end in LDS,
// writes final node values directly. No partial arrays, no reduce kernels, no fences.
// memset + 4 kernels = 5 dispatches (was 8), ~18 MB traffic (was ~36 MB).

// ---- K1: write-combined radix partition into 256 dense buckets ----
__global__ __launch_bounds__(256)
void k_part(const int* __restrict__ row, const int* __restrict__ col,
            unsigned* __restrict__ tails, unsigned* __restrict__ bks) {
    __shared__ unsigned stage[NB * CAPB];           // 32 KB
    __shared__ unsigned cnt[NB], gpos[NB];
    const int t  = threadIdx.x;
    const int e0 = blockIdx.x * PCHUNK;
    cnt[t] = 0u;                                    // 256 threads == NB counters
    __syncthreads();
    const int4* c4 = (const int4*)(col + e0);
    const int4* r4 = (const int4*)(row + e0);
    for (int i = t; i < PCHUNK / 4; i += 256) {     // 400 int4s
        int4 cv = c4[i];
        int4 rv = r4[i];
#pragma unroll
        for (int k = 0; k < 4; ++k) {
            int c = (&cv.x)[k], r = (&rv.x)[k];
            int b = c / SL;                         // magic-mul div
            unsigned off = atomicAdd(&cnt[b], 1u);
            if (off < CAPB)
                stage[(b << 5) + off] = ((unsigned)(c - b * SL) << 16) | (unsigned)r;
        }
    }
    __syncthreads();
    {
        unsigned cc = min(cnt[t], (unsigned)CAPB);
        cnt[t]  = cc;
        gpos[t] = atomicAdd(&tails[t], cc);         // 128K global atomics, 256 addresses
    }
    __syncthreads();
    // dense flush: contiguous per-bucket segments
    for (int i = t; i < NB * CAPB; i += 256) {
        int b = i >> 5; unsigned o = (unsigned)(i & 31);
        if (o < cnt[b]) {
            unsigned dst = gpos[b] + o;
            if (dst < BCAP) bks[(size_t)b * BCAP + dst] = stage[i];
        }
    }
}

// ---- K2: per-bucket degree histogram -> dinv, g  (one block per bucket) ----
__global__ __launch_bounds__(256)
void k_dg(const unsigned* __restrict__ tails, const unsigned* __restrict__ bks,
          const float* __restrict__ x, float* __restrict__ dinv, float* __restrict__ g) {
    __shared__ unsigned acc[SL];                    // 784 B
    const int t = threadIdx.x, b = blockIdx.x;
    if (t < SL) acc[t] = 0u;
    __syncthreads();
    unsigned tail = min(tails[b], (unsigned)BCAP);
    const unsigned* bk = bks + (size_t)b * BCAP;
    const uint4* bk4 = (const uint4*)bk;
    unsigned hv = tail & ~3u;
    for (unsigned i = t; (i << 2) < hv; i += 256) {
        uint4 v = bk4[i];
        atomicAdd(&acc[v.x >> 16], 1u);
        atomicAdd(&acc[v.y >> 16], 1u);
        atomicAdd(&acc[v.z >> 16], 1u);
        atomicAdd(&acc[v.w >> 16], 1u);
    }
    for (unsigned i = hv + t; i < tail; i += 256)
        atomicAdd(&acc[bk[i] >> 16], 1u);
    __syncthreads();
    if (t < SL) {
        int n = b * SL + t;
        if (n < N_NODES) {
            float di = rsqrtf((float)(acc[t] + 1u));    // +1 self-loop
            dinv[n] = di;
            g[n] = di * x[n];
        }
    }
}

// ---- K3: layer-1 aggregation + fused MLP -> z  (one block per bucket) ----
__global__ __launch_bounds__(256)
void k_a1(const unsigned* __restrict__ tails, const unsigned* __restrict__ bks,
          const float* __restrict__ g, const float* __restrict__ dinv,
          const float* __restrict__ W1, const float* __restrict__ b1,
          const float* __restrict__ W2, float2* __restrict__ z) {
    __shared__ float acc[SL];
    const int t = threadIdx.x, b = blockIdx.x;
    if (t < SL) acc[t] = 0.0f;
    __syncthreads();
    unsigned tail = min(tails[b], (unsigned)BCAP);
    const unsigned* bk = bks + (size_t)b * BCAP;
    const uint4* bk4 = (const uint4*)bk;
    unsigned hv = tail & ~3u;
    for (unsigned i = t; (i << 2) < hv; i += 256) {
        uint4 v = bk4[i];
        float g0 = g[v.x & 0xFFFFu];
        float g1 = g[v.y & 0xFFFFu];
        float g2 = g[v.z & 0xFFFFu];
        float g3 = g[v.w & 0xFFFFu];
        atomicAdd(&acc[v.x >> 16], g0);
        atomicAdd(&acc[v.y >> 16], g1);
        atomicAdd(&acc[v.z >> 16], g2);
        atomicAdd(&acc[v.w >> 16], g3);
    }
    for (unsigned i = hv + t; i < tail; i += 256) {
        unsigned v = bk[i];
        atomicAdd(&acc[v >> 16], g[v & 0xFFFFu]);
    }
    __syncthreads();
    if (t < SL) {
        int n = b * SL + t;
        if (n < N_NODES) {
            float di = dinv[n];
            float sv = di * (acc[t] + g[n]);        // + self-loop message
            float y0 = 0.0f, y1 = 0.0f;
#pragma unroll
            for (int k = 0; k < HIDDEN; ++k) {      // wave-uniform -> s_load
                float h = fmaxf(sv * W1[k] + b1[k], 0.0f);
                y0 += h * W2[2 * k];
                y1 += h * W2[2 * k + 1];
            }
            z[n] = make_float2(di * y0, di * y1);
        }
    }
}

// ---- K4: layer-2 aggregation (float2) + epilogue -> out  (one block per bucket) ----
__global__ __launch_bounds__(256)
void k_a2(const unsigned* __restrict__ tails, const unsigned* __restrict__ bks,
          const float2* __restrict__ z, const float* __restrict__ dinv,
          const float* __restrict__ b2, float2* __restrict__ out) {
    __shared__ float ax[SL];
    __shared__ float ay[SL];
    const int t = threadIdx.x, b = blockIdx.x;
    if (t < SL) { ax[t] = 0.0f; ay[t] = 0.0f; }
    __syncthreads();
    unsigned tail = min(tails[b], (unsigned)BCAP);
    const unsigned* bk = bks + (size_t)b * BCAP;
    const uint4* bk4 = (const uint4*)bk;
    unsigned hv = tail & ~3u;
    for (unsigned i = t; (i << 2) < hv; i += 256) {
        uint4 v = bk4[i];
        float2 z0 = z[v.x & 0xFFFFu];
        float2 z1 = z[v.y & 0xFFFFu];
        float2 z2 = z[v.z & 0xFFFFu];
        float2 z3 = z[v.w & 0xFFFFu];
        atomicAdd(&ax[v.x >> 16], z0.x); atomicAdd(&ay[v.x >> 16], z0.y);
        atomicAdd(&ax[v.y >> 16], z1.x); atomicAdd(&ay[v.y >> 16], z1.y);
        atomicAdd(&ax[v.z >> 16], z2.x); atomicAdd(&ay[v.z >> 16], z2.y);
        atomicAdd(&ax[v.w >> 16], z3.x); atomicAdd(&ay[v.w >> 16], z3.y);
    }
    for (unsigned i = hv + t; i < tail; i += 256) {
        unsigned v = bk[i];
        float2 zz = z[v & 0xFFFFu];
        atomicAdd(&ax[v >> 16], zz.x);
        atomicAdd(&ay[v >> 16], zz.y);
    }
    __syncthreads();
    if (t < SL) {
        int n = b * SL + t;
        if (n < N_NODES) {
            float di = dinv[n];
            float2 zn = z[n];
            out[n] = make_float2(di * (ax[t] + zn.x) + b2[0],
                                 di * (ay[t] + zn.y) + b2[1]);
        }
    }
}

// ================= launch =================

extern "C" void kernel_launch(void* const* d_in, const int* in_sizes, int n_in,
                              void* d_out, int out_size, void* d_ws, size_t ws_size,
                              hipStream_t stream) {
    const float* x  = (const float*)d_in[0];
    const int*   ei = (const int*)d_in[1];
    const float* W1 = (const float*)d_in[2];
    const float* b1 = (const float*)d_in[3];
    const float* W2 = (const float*)d_in[4];
    const float* b2 = (const float*)d_in[5];

    const int* row = ei;
    const int* col = ei + N_EDGES;

    char* p = (char*)d_ws;
    unsigned* tails = (unsigned*)p;  p += 1024 + 128;                  // 256 u32 (+pad)
    unsigned* bks   = (unsigned*)p;  p += (size_t)NB * BCAP * 4;       // 3.7 MB
    float*    dinv  = (float*)p;     p += 200064;
    float*    g     = (float*)p;     p += 200064;
    float2*   z     = (float2*)p;

    hipMemsetAsync(tails, 0, NB * sizeof(unsigned), stream);
    k_part<<<NPART, 256, 0, stream>>>(row, col, tails, bks);
    k_dg  <<<NB,    256, 0, stream>>>(tails, bks, x, dinv, g);
    k_a1  <<<NB,    256, 0, stream>>>(tails, bks, g, dinv, W1, b1, W2, z);
    k_a2  <<<NB,    256, 0, stream>>>(tails, bks, z, dinv, b2, (float2*)d_out);
}